// Round 1
// baseline (13103.464 us; speedup 1.0000x reference)
//
#include <hip/hip_runtime.h>

// Problem constants (match reference)
#define TT 4096   // sequence length (torch "batch" acting as time)
#define SD 64     // shared features
#define PD 8      // per-device features
#define DD 32     // devices
#define HH 128    // hidden
#define NG 512    // 4*H gate rows
#define XD 72     // S+P
#define XPAIRS 36 // packed bf16x2 pairs of x
#define WROW 37   // padded row stride (uints) for W_ih0 in LDS (gcd(37,32)=1 -> conflict-free)

typedef __bf16 bf16x2 __attribute__((ext_vector_type(2)));

#if defined(__has_builtin)
#  if __has_builtin(__builtin_amdgcn_fdot2_f32_bf16)
#    define USE_DOT2 1
#  endif
#endif

// round-to-nearest-even fp32 -> bf16, pack two into one uint (a = low element)
__device__ __forceinline__ unsigned rne_pack(float a, float b) {
  unsigned ua = __builtin_bit_cast(unsigned, a);
  unsigned ub = __builtin_bit_cast(unsigned, b);
  ua = (ua + 0x7fffu + ((ua >> 16) & 1u)) >> 16;
  ub = (ub + 0x7fffu + ((ub >> 16) & 1u)) >> 16;
  return (ub << 16) | (ua & 0xffffu);
}

__device__ __forceinline__ unsigned short rne1(float a) {
  unsigned ua = __builtin_bit_cast(unsigned, a);
  return (unsigned short)((ua + 0x7fffu + ((ua >> 16) & 1u)) >> 16);
}

// acc += dot(bf16x2 w, bf16x2 h), fp32 accumulate
__device__ __forceinline__ float dot2(unsigned w, unsigned h, float acc) {
#ifdef USE_DOT2
  return __builtin_amdgcn_fdot2_f32_bf16(__builtin_bit_cast(bf16x2, w),
                                         __builtin_bit_cast(bf16x2, h), acc, false);
#else
  float w0 = __builtin_bit_cast(float, w << 16);
  float w1 = __builtin_bit_cast(float, w & 0xffff0000u);
  float h0 = __builtin_bit_cast(float, h << 16);
  float h1 = __builtin_bit_cast(float, h & 0xffff0000u);
  return __builtin_fmaf(w1, h1, __builtin_fmaf(w0, h0, acc));
#endif
}

__device__ __forceinline__ float fast_sigmoid(float x) {
  return 1.0f / (1.0f + __expf(-x));
}
__device__ __forceinline__ float fast_tanh(float x) {
  return 2.0f / (1.0f + __expf(-2.0f * x)) - 1.0f;
}

__global__ __launch_bounds__(512, 2)
void lstm_pd_kernel(const float* __restrict__ shared_in,   // [T, S]
                    const float* __restrict__ perdev,      // [D, T, P]
                    const float* __restrict__ Wih0,        // [D, 4H, S+P]
                    const float* __restrict__ Whh0,        // [D, 4H, H]
                    const float* __restrict__ b0,          // [D, 4H]
                    const float* __restrict__ Wih1,        // [D, 4H, H]
                    const float* __restrict__ Whh1,        // [D, 4H, H]
                    const float* __restrict__ b1,          // [D, 4H]
                    const float* __restrict__ Wout,        // [D, H]
                    const float* __restrict__ bout,        // [D]
                    float* __restrict__ out)               // [T, D]
{
  const int d = blockIdx.x;        // device
  const int g = threadIdx.x;       // gate row 0..511
  const int lane = g & 63;
  const int wave = g >> 6;

  __shared__ float act_s[NG];                          // gate activations exchange
  __shared__ __align__(16) unsigned h0_s[HH / 2];      // h0 packed bf16x2
  __shared__ __align__(16) unsigned h1_s[HH / 2];      // h1 packed bf16x2
  __shared__ __align__(16) unsigned x_s[XPAIRS + 4];   // x_t packed bf16x2
  __shared__ unsigned wih0_s[NG * WROW];               // W_ih0 rows, packed bf16x2, padded stride
  __shared__ float part_s[2];                          // output reduction partials

  // ---- setup: recurrent weights -> registers (bf16 packed) ----
  unsigned wa[HH / 2];  // W_hh0 row g
  unsigned wi[HH / 2];  // W_ih1 row g
  unsigned wh[HH / 2];  // W_hh1 row g
  {
    const float* p = Whh0 + (size_t)(d * NG + g) * HH;
#pragma unroll
    for (int j = 0; j < HH / 2; ++j) wa[j] = rne_pack(p[2 * j], p[2 * j + 1]);
  }
  {
    const float* p = Wih1 + (size_t)(d * NG + g) * HH;
#pragma unroll
    for (int j = 0; j < HH / 2; ++j) wi[j] = rne_pack(p[2 * j], p[2 * j + 1]);
  }
  {
    const float* p = Whh1 + (size_t)(d * NG + g) * HH;
#pragma unroll
    for (int j = 0; j < HH / 2; ++j) wh[j] = rne_pack(p[2 * j], p[2 * j + 1]);
  }
  // W_ih0 row g -> LDS (bf16 packed)
  {
    const float* p = Wih0 + (size_t)(d * NG + g) * XD;
    for (int j = 0; j < XPAIRS; ++j) wih0_s[g * WROW + j] = rne_pack(p[2 * j], p[2 * j + 1]);
  }
  const float b0g = b0[d * NG + g];
  const float b1g = b1[d * NG + g];
  const bool is_tanh_gate = ((g >> 7) == 2);  // rows 256..383 = candidate gate (i,f,g,o order)
  float c0 = 0.f, c1 = 0.f;                   // cell state, owned by threads g<128
  const float woutu = (g < HH) ? Wout[d * HH + g] : 0.f;
  const float boutd = bout[d];

  if (g < HH / 2) { h0_s[g] = 0u; h1_s[g] = 0u; }

  // prefetch x for t=0
  float xa = 0.f, xb = 0.f;
  if (g < XPAIRS) {
    if (g < SD / 2) {
      xa = shared_in[0 * SD + 2 * g];
      xb = shared_in[0 * SD + 2 * g + 1];
    } else {
      int k = 2 * (g - SD / 2);
      xa = perdev[((size_t)d * TT + 0) * PD + k];
      xb = perdev[((size_t)d * TT + 0) * PD + k + 1];
    }
  }

  __syncthreads();

  for (int t = 0; t < TT; ++t) {
    // ---- phase 1: publish x_t ----
    if (g < XPAIRS) x_s[g] = rne_pack(xa, xb);
    __syncthreads();  // barrier 1

    // deferred output store for t-1 (part_s written before barrier 1)
    if (g == 0 && t > 0) out[(size_t)(t - 1) * DD + d] = part_s[0] + part_s[1] + boutd;

    // prefetch x for t+1 (latency hidden behind phase 2-4 compute)
    if (g < XPAIRS && t + 1 < TT) {
      int tn = t + 1;
      if (g < SD / 2) {
        xa = shared_in[tn * SD + 2 * g];
        xb = shared_in[tn * SD + 2 * g + 1];
      } else {
        int k = 2 * (g - SD / 2);
        xa = perdev[((size_t)d * TT + tn) * PD + k];
        xb = perdev[((size_t)d * TT + tn) * PD + k + 1];
      }
    }

    // ---- phase 2: gates0[g] = b0 + Wih0_row . x_t + Whh0_row . h0 ----
    float a0 = b0g, a1 = 0.f, a2 = 0.f, a3 = 0.f;
    {
      const unsigned* wrow = &wih0_s[g * WROW];
#pragma unroll
      for (int j = 0; j < XPAIRS; j += 4) {
        a0 = dot2(wrow[j + 0], x_s[j + 0], a0);
        a1 = dot2(wrow[j + 1], x_s[j + 1], a1);
        a2 = dot2(wrow[j + 2], x_s[j + 2], a2);
        a3 = dot2(wrow[j + 3], x_s[j + 3], a3);
      }
      const uint4* h4 = (const uint4*)h0_s;
#pragma unroll
      for (int k = 0; k < HH / 8; ++k) {
        uint4 hv = h4[k];
        a0 = dot2(wa[4 * k + 0], hv.x, a0);
        a1 = dot2(wa[4 * k + 1], hv.y, a1);
        a2 = dot2(wa[4 * k + 2], hv.z, a2);
        a3 = dot2(wa[4 * k + 3], hv.w, a3);
      }
    }
    {
      float pre = (a0 + a1) + (a2 + a3);
      act_s[g] = is_tanh_gate ? fast_tanh(pre) : fast_sigmoid(pre);
    }
    __syncthreads();  // barrier 2

    // ---- phase 3: layer-0 cell update (threads 0..127) ----
    if (g < HH) {
      float ig = act_s[g], fg = act_s[g + 128], gg = act_s[g + 256], og = act_s[g + 384];
      c0 = __builtin_fmaf(fg, c0, ig * gg);
      float h0n = og * fast_tanh(c0);
      ((unsigned short*)h0_s)[g] = rne1(h0n);
    }
    __syncthreads();  // barrier 3

    // ---- phase 4: gates1[g] = b1 + Wih1_row . h0_new + Whh1_row . h1 ----
    a0 = b1g; a1 = 0.f; a2 = 0.f; a3 = 0.f;
    {
      const uint4* h4 = (const uint4*)h0_s;
#pragma unroll
      for (int k = 0; k < HH / 8; ++k) {
        uint4 hv = h4[k];
        a0 = dot2(wi[4 * k + 0], hv.x, a0);
        a1 = dot2(wi[4 * k + 1], hv.y, a1);
        a2 = dot2(wi[4 * k + 2], hv.z, a2);
        a3 = dot2(wi[4 * k + 3], hv.w, a3);
      }
      const uint4* g4 = (const uint4*)h1_s;
#pragma unroll
      for (int k = 0; k < HH / 8; ++k) {
        uint4 hv = g4[k];
        a0 = dot2(wh[4 * k + 0], hv.x, a0);
        a1 = dot2(wh[4 * k + 1], hv.y, a1);
        a2 = dot2(wh[4 * k + 2], hv.z, a2);
        a3 = dot2(wh[4 * k + 3], hv.w, a3);
      }
    }
    {
      float pre = (a0 + a1) + (a2 + a3);
      act_s[g] = is_tanh_gate ? fast_tanh(pre) : fast_sigmoid(pre);
    }
    __syncthreads();  // barrier 4

    // ---- phase 5: layer-1 cell update + output partial (threads 0..127) ----
    if (g < HH) {
      float ig = act_s[g], fg = act_s[g + 128], gg = act_s[g + 256], og = act_s[g + 384];
      c1 = __builtin_fmaf(fg, c1, ig * gg);
      float h1n = og * fast_tanh(c1);
      ((unsigned short*)h1_s)[g] = rne1(h1n);
      float p = woutu * h1n;
#pragma unroll
      for (int off = 32; off > 0; off >>= 1) p += __shfl_down(p, off, 64);
      if (lane == 0) part_s[wave] = p;
    }
    // no barrier here: barrier 1 of next iteration orders part_s/h1_s
    // writes before their readers, and phase-5 reads of act_s complete
    // before any thread passes barrier 1.
  }

  __syncthreads();
  if (g == 0) out[(size_t)(TT - 1) * DD + d] = part_s[0] + part_s[1] + boutd;
}

extern "C" void kernel_launch(void* const* d_in, const int* in_sizes, int n_in,
                              void* d_out, int out_size, void* d_ws, size_t ws_size,
                              hipStream_t stream) {
  const float* shared_in = (const float*)d_in[0];
  const float* perdev    = (const float*)d_in[1];
  const float* Wih0      = (const float*)d_in[2];
  const float* Whh0      = (const float*)d_in[3];
  const float* b0        = (const float*)d_in[4];
  const float* Wih1      = (const float*)d_in[5];
  const float* Whh1      = (const float*)d_in[6];
  const float* b1        = (const float*)d_in[7];
  const float* Wout      = (const float*)d_in[8];
  const float* bout      = (const float*)d_in[9];
  float* out = (float*)d_out;

  lstm_pd_kernel<<<dim3(DD), dim3(NG), 0, stream>>>(
      shared_in, perdev, Wih0, Whh0, b0, Wih1, Whh1, b1, Wout, bout, out);
}

// Round 2
// 9323.830 us; speedup vs baseline: 1.4054x; 1.4054x over previous
//
#include <hip/hip_runtime.h>

// Problem constants (match reference)
#define TT 4096   // sequence length (torch "batch" acting as time)
#define SD 64     // shared features
#define PD 8      // per-device features
#define DD 32     // devices
#define HH 128    // hidden
#define NG 512    // 4*H gate rows
#define XD 72     // S+P
#define XPAIRS 36 // packed bf16x2 pairs of x
#define WROW 37   // padded row stride (uints) for W_ih0 in LDS (gcd(37,32)=1 -> 2-way, free per m136)

typedef __bf16 bf16x2 __attribute__((ext_vector_type(2)));
// 16 packed bf16x2 pairs held as a first-class SSA vector value -> guaranteed
// register allocation (no alloca -> no scratch spill, the R1 pathology).
typedef unsigned uv16 __attribute__((ext_vector_type(16)));

#if defined(__has_builtin)
#  if __has_builtin(__builtin_amdgcn_fdot2_f32_bf16)
#    define USE_DOT2 1
#  endif
#endif

// round-to-nearest-even fp32 -> bf16, pack two into one uint (a = low element)
__device__ __forceinline__ unsigned rne_pack(float a, float b) {
  unsigned ua = __builtin_bit_cast(unsigned, a);
  unsigned ub = __builtin_bit_cast(unsigned, b);
  ua = (ua + 0x7fffu + ((ua >> 16) & 1u)) >> 16;
  ub = (ub + 0x7fffu + ((ub >> 16) & 1u)) >> 16;
  return (ub << 16) | (ua & 0xffffu);
}

__device__ __forceinline__ unsigned short rne1(float a) {
  unsigned ua = __builtin_bit_cast(unsigned, a);
  return (unsigned short)((ua + 0x7fffu + ((ua >> 16) & 1u)) >> 16);
}

// acc += dot(bf16x2 w, bf16x2 h), fp32 accumulate
__device__ __forceinline__ float dot2(unsigned w, unsigned h, float acc) {
#ifdef USE_DOT2
  return __builtin_amdgcn_fdot2_f32_bf16(__builtin_bit_cast(bf16x2, w),
                                         __builtin_bit_cast(bf16x2, h), acc, false);
#else
  float w0 = __builtin_bit_cast(float, w << 16);
  float w1 = __builtin_bit_cast(float, w & 0xffff0000u);
  float h0 = __builtin_bit_cast(float, h << 16);
  float h1 = __builtin_bit_cast(float, h & 0xffff0000u);
  return __builtin_fmaf(w1, h1, __builtin_fmaf(w0, h0, acc));
#endif
}

// load 32 consecutive floats, pack to 16 bf16x2 uints in an SSA vector
__device__ __forceinline__ uv16 load16(const float* __restrict__ p) {
  uv16 v;
#pragma unroll
  for (int j = 0; j < 16; ++j) v[j] = rne_pack(p[2 * j], p[2 * j + 1]);
  return v;
}

// 16 dot2s: one uv16 weight chunk against h pairs [base*4 .. base*4+15]
__device__ __forceinline__ void dot16(uv16 w, const uint4* __restrict__ h4, int base,
                                      float& a0, float& a1, float& a2, float& a3) {
#pragma unroll
  for (int k = 0; k < 4; ++k) {
    uint4 hv = h4[base + k];
    a0 = dot2(w[4 * k + 0], hv.x, a0);
    a1 = dot2(w[4 * k + 1], hv.y, a1);
    a2 = dot2(w[4 * k + 2], hv.z, a2);
    a3 = dot2(w[4 * k + 3], hv.w, a3);
  }
}

__device__ __forceinline__ float fast_sigmoid(float x) {
  return 1.0f / (1.0f + __expf(-x));
}
__device__ __forceinline__ float fast_tanh(float x) {
  return 2.0f / (1.0f + __expf(-2.0f * x)) - 1.0f;
}

__global__ __attribute__((amdgpu_flat_work_group_size(512, 512), amdgpu_waves_per_eu(2, 2)))
void lstm_pd_kernel(const float* __restrict__ shared_in,   // [T, S]
                    const float* __restrict__ perdev,      // [D, T, P]
                    const float* __restrict__ Wih0,        // [D, 4H, S+P]
                    const float* __restrict__ Whh0,        // [D, 4H, H]
                    const float* __restrict__ b0,          // [D, 4H]
                    const float* __restrict__ Wih1,        // [D, 4H, H]
                    const float* __restrict__ Whh1,        // [D, 4H, H]
                    const float* __restrict__ b1,          // [D, 4H]
                    const float* __restrict__ Wout,        // [D, H]
                    const float* __restrict__ bout,        // [D]
                    float* __restrict__ out)               // [T, D]
{
  const int d = blockIdx.x;        // device
  const int g = threadIdx.x;       // gate row 0..511
  const int lane = g & 63;
  const int wave = g >> 6;

  __shared__ float act_s[NG];                          // gate activations exchange
  __shared__ __align__(16) unsigned h0_s[HH / 2];      // h0 packed bf16x2
  __shared__ __align__(16) unsigned h1_s[HH / 2];      // h1 packed bf16x2
  __shared__ __align__(16) unsigned x_s[XPAIRS + 4];   // x_t packed bf16x2
  __shared__ unsigned wih0_s[NG * WROW];               // W_ih0 rows, packed bf16x2, padded stride
  __shared__ float part_s[2];                          // output reduction partials

  // ---- setup: recurrent weights -> registers (bf16 packed, SSA vectors) ----
  const float* pa = Whh0 + (size_t)(d * NG + g) * HH;
  uv16 wa0 = load16(pa + 0), wa1 = load16(pa + 32), wa2 = load16(pa + 64), wa3 = load16(pa + 96);
  const float* pi = Wih1 + (size_t)(d * NG + g) * HH;
  uv16 wi0 = load16(pi + 0), wi1 = load16(pi + 32), wi2 = load16(pi + 64), wi3 = load16(pi + 96);
  const float* ph = Whh1 + (size_t)(d * NG + g) * HH;
  uv16 wh0 = load16(ph + 0), wh1 = load16(ph + 32), wh2 = load16(ph + 64), wh3 = load16(ph + 96);

  // W_ih0 row g -> LDS (bf16 packed)
  {
    const float* p = Wih0 + (size_t)(d * NG + g) * XD;
    for (int j = 0; j < XPAIRS; ++j) wih0_s[g * WROW + j] = rne_pack(p[2 * j], p[2 * j + 1]);
  }
  const float b0g = b0[d * NG + g];
  const float b1g = b1[d * NG + g];
  const bool is_tanh_gate = ((g >> 7) == 2);  // rows 256..383 = candidate gate (i,f,g,o order)
  float c0 = 0.f, c1 = 0.f;                   // cell state, owned by threads g<128
  const float woutu = (g < HH) ? Wout[d * HH + g] : 0.f;
  const float boutd = bout[d];

  if (g < HH / 2) { h0_s[g] = 0u; h1_s[g] = 0u; }

  // prefetch x for t=0
  float xa = 0.f, xb = 0.f;
  if (g < XPAIRS) {
    if (g < SD / 2) {
      xa = shared_in[0 * SD + 2 * g];
      xb = shared_in[0 * SD + 2 * g + 1];
    } else {
      int k = 2 * (g - SD / 2);
      xa = perdev[((size_t)d * TT + 0) * PD + k];
      xb = perdev[((size_t)d * TT + 0) * PD + k + 1];
    }
  }

  __syncthreads();

  for (int t = 0; t < TT; ++t) {
    // ---- phase 1: publish x_t ----
    if (g < XPAIRS) x_s[g] = rne_pack(xa, xb);
    __syncthreads();  // barrier 1

    // deferred output store for t-1 (part_s written before barrier 1)
    if (g == 0 && t > 0) out[(size_t)(t - 1) * DD + d] = part_s[0] + part_s[1] + boutd;

    // prefetch x for t+1 (latency hidden behind phase 2-4 compute)
    if (g < XPAIRS && t + 1 < TT) {
      int tn = t + 1;
      if (g < SD / 2) {
        xa = shared_in[tn * SD + 2 * g];
        xb = shared_in[tn * SD + 2 * g + 1];
      } else {
        int k = 2 * (g - SD / 2);
        xa = perdev[((size_t)d * TT + tn) * PD + k];
        xb = perdev[((size_t)d * TT + tn) * PD + k + 1];
      }
    }

    // ---- phase 2: gates0[g] = b0 + Wih0_row . x_t + Whh0_row . h0 ----
    float a0 = b0g, a1 = 0.f, a2 = 0.f, a3 = 0.f;
    {
      const unsigned* wrow = &wih0_s[g * WROW];
#pragma unroll
      for (int j = 0; j < XPAIRS; j += 4) {
        a0 = dot2(wrow[j + 0], x_s[j + 0], a0);
        a1 = dot2(wrow[j + 1], x_s[j + 1], a1);
        a2 = dot2(wrow[j + 2], x_s[j + 2], a2);
        a3 = dot2(wrow[j + 3], x_s[j + 3], a3);
      }
      const uint4* h4 = (const uint4*)h0_s;
      dot16(wa0, h4, 0, a0, a1, a2, a3);
      dot16(wa1, h4, 4, a0, a1, a2, a3);
      dot16(wa2, h4, 8, a0, a1, a2, a3);
      dot16(wa3, h4, 12, a0, a1, a2, a3);
    }
    {
      float pre = (a0 + a1) + (a2 + a3);
      act_s[g] = is_tanh_gate ? fast_tanh(pre) : fast_sigmoid(pre);
    }
    __syncthreads();  // barrier 2

    // ---- phase 3: layer-0 cell update (threads 0..127) ----
    if (g < HH) {
      float ig = act_s[g], fg = act_s[g + 128], gg = act_s[g + 256], og = act_s[g + 384];
      c0 = __builtin_fmaf(fg, c0, ig * gg);
      float h0n = og * fast_tanh(c0);
      ((unsigned short*)h0_s)[g] = rne1(h0n);
    }
    __syncthreads();  // barrier 3

    // ---- phase 4: gates1[g] = b1 + Wih1_row . h0_new + Whh1_row . h1 ----
    a0 = b1g; a1 = 0.f; a2 = 0.f; a3 = 0.f;
    {
      const uint4* h4 = (const uint4*)h0_s;
      dot16(wi0, h4, 0, a0, a1, a2, a3);
      dot16(wi1, h4, 4, a0, a1, a2, a3);
      dot16(wi2, h4, 8, a0, a1, a2, a3);
      dot16(wi3, h4, 12, a0, a1, a2, a3);
      const uint4* g4 = (const uint4*)h1_s;
      dot16(wh0, g4, 0, a0, a1, a2, a3);
      dot16(wh1, g4, 4, a0, a1, a2, a3);
      dot16(wh2, g4, 8, a0, a1, a2, a3);
      dot16(wh3, g4, 12, a0, a1, a2, a3);
    }
    {
      float pre = (a0 + a1) + (a2 + a3);
      act_s[g] = is_tanh_gate ? fast_tanh(pre) : fast_sigmoid(pre);
    }
    __syncthreads();  // barrier 4

    // ---- phase 5: layer-1 cell update + output partial (threads 0..127) ----
    if (g < HH) {
      float ig = act_s[g], fg = act_s[g + 128], gg = act_s[g + 256], og = act_s[g + 384];
      c1 = __builtin_fmaf(fg, c1, ig * gg);
      float h1n = og * fast_tanh(c1);
      ((unsigned short*)h1_s)[g] = rne1(h1n);
      float p = woutu * h1n;
#pragma unroll
      for (int off = 32; off > 0; off >>= 1) p += __shfl_down(p, off, 64);
      if (lane == 0) part_s[wave] = p;
    }
    // no barrier here: barrier 1 of next iteration orders part_s/h1_s
    // writes before their readers, and phase-5 reads of act_s complete
    // before any thread passes barrier 1.
  }

  __syncthreads();
  if (g == 0) out[(size_t)(TT - 1) * DD + d] = part_s[0] + part_s[1] + boutd;
}

extern "C" void kernel_launch(void* const* d_in, const int* in_sizes, int n_in,
                              void* d_out, int out_size, void* d_ws, size_t ws_size,
                              hipStream_t stream) {
  const float* shared_in = (const float*)d_in[0];
  const float* perdev    = (const float*)d_in[1];
  const float* Wih0      = (const float*)d_in[2];
  const float* Whh0      = (const float*)d_in[3];
  const float* b0        = (const float*)d_in[4];
  const float* Wih1      = (const float*)d_in[5];
  const float* Whh1      = (const float*)d_in[6];
  const float* b1        = (const float*)d_in[7];
  const float* Wout      = (const float*)d_in[8];
  const float* bout      = (const float*)d_in[9];
  float* out = (float*)d_out;

  lstm_pd_kernel<<<dim3(DD), dim3(NG), 0, stream>>>(
      shared_in, perdev, Wih0, Whh0, b0, Wih1, Whh1, b1, Wout, bout, out);
}

// Round 3
// 7151.718 us; speedup vs baseline: 1.8322x; 1.3037x over previous
//
#include <hip/hip_runtime.h>

// Problem constants (match reference)
#define TT 4096   // sequence length (torch "batch" acting as time)
#define SD 64     // shared features
#define PD 8      // per-device features
#define DD 32     // devices
#define HH 128    // hidden
#define NG 512    // 4*H gate rows
#define XD 72     // S+P
#define XPAIRS 36 // packed f16x2 pairs of x
#define WROW 37   // padded row stride (uints) for W_ih0 in LDS (fallback path)
#define GXTB 16   // t-tile of the gx precompute kernel

typedef _Float16 h2 __attribute__((ext_vector_type(2)));
typedef unsigned uv16 __attribute__((ext_vector_type(16)));
typedef unsigned uv4 __attribute__((ext_vector_type(4)));

#if defined(__has_builtin)
#  if __has_builtin(__builtin_amdgcn_fdot2)
#    define USE_DOT2 1
#  endif
#  if __has_builtin(__builtin_amdgcn_sched_barrier)
#    define SB() __builtin_amdgcn_sched_barrier(0)
#  endif
#endif
#ifndef SB
#  define SB()
#endif

// pack two floats into one uint of f16x2 (a = low element), RTE
__device__ __forceinline__ unsigned pack_h2(float a, float b) {
  unsigned short ua = __builtin_bit_cast(unsigned short, (_Float16)a);
  unsigned short ub = __builtin_bit_cast(unsigned short, (_Float16)b);
  return ((unsigned)ub << 16) | ua;
}
__device__ __forceinline__ unsigned short f16bits(float a) {
  return __builtin_bit_cast(unsigned short, (_Float16)a);
}
__device__ __forceinline__ float f16val(unsigned short u) {
  return (float)__builtin_bit_cast(_Float16, u);
}

// acc += dot(f16x2 w, f16x2 h), fp32 accumulate (v_dot2_f32_f16)
__device__ __forceinline__ float dot2(unsigned w, unsigned h, float acc) {
#ifdef USE_DOT2
  return __builtin_amdgcn_fdot2(__builtin_bit_cast(h2, w),
                                __builtin_bit_cast(h2, h), acc, false);
#else
  h2 wv = __builtin_bit_cast(h2, w), hv = __builtin_bit_cast(h2, h);
  return __builtin_fmaf((float)wv[1], (float)hv[1],
                        __builtin_fmaf((float)wv[0], (float)hv[0], acc));
#endif
}

// load 32 consecutive floats, pack to 16 f16x2 uints in an SSA vector
__device__ __forceinline__ uv16 load16(const float* __restrict__ p) {
  uv16 v;
#pragma unroll
  for (int j = 0; j < 16; ++j) v[j] = pack_h2(p[2 * j], p[2 * j + 1]);
  return v;
}

// 16 dot2s: one uv16 weight chunk against h pairs [base*4 .. base*4+15]
__device__ __forceinline__ void dot16(uv16 w, const uint4* __restrict__ h4, int base,
                                      float& a0, float& a1, float& a2, float& a3) {
#pragma unroll
  for (int k = 0; k < 4; ++k) {
    uint4 hv = h4[base + k];
    a0 = dot2(w[4 * k + 0], hv.x, a0);
    a1 = dot2(w[4 * k + 1], hv.y, a1);
    a2 = dot2(w[4 * k + 2], hv.z, a2);
    a3 = dot2(w[4 * k + 3], hv.w, a3);
  }
}

__device__ __forceinline__ float fast_sigmoid(float x) {
  return 1.0f / (1.0f + __expf(-x));
}
__device__ __forceinline__ float fast_tanh(float x) {
  return 2.0f / (1.0f + __expf(-2.0f * x)) - 1.0f;
}

// ---------------------------------------------------------------------------
// gx precompute: gx[d][t][g] = f16( b0[d][g] + W_ih0[d][g][:] . x[d][t][:] )
// No sequential dependence -> fully parallel GEMM-shaped kernel.
// ---------------------------------------------------------------------------
__global__ __launch_bounds__(512)
void gx_kernel(const float* __restrict__ shared_in,  // [T, S]
               const float* __restrict__ perdev,     // [D, T, P]
               const float* __restrict__ Wih0,       // [D, 4H, S+P]
               const float* __restrict__ b0,         // [D, 4H]
               unsigned short* __restrict__ gx)      // [D, T, 4H] f16
{
  const int d = blockIdx.y;
  const int t0 = blockIdx.x * GXTB;
  const int g = threadIdx.x;

  __shared__ unsigned xs[GXTB * XPAIRS];  // x tile, packed f16x2

  // W_ih0 row g -> registers (SSA vectors, constant-indexed)
  const float* p = Wih0 + (size_t)(d * NG + g) * XD;
  uv16 w0, w1;
  uv4 w2;
#pragma unroll
  for (int j = 0; j < 16; ++j) w0[j] = pack_h2(p[2 * j], p[2 * j + 1]);
#pragma unroll
  for (int j = 0; j < 16; ++j) w1[j] = pack_h2(p[32 + 2 * j], p[33 + 2 * j]);
#pragma unroll
  for (int j = 0; j < 4; ++j) w2[j] = pack_h2(p[64 + 2 * j], p[65 + 2 * j]);
  const float b0g = b0[d * NG + g];

  // stage x tile
  for (int i = g; i < GXTB * XPAIRS; i += 512) {
    int r = i / XPAIRS, j = i - r * XPAIRS, t = t0 + r;
    float a, b;
    if (j < SD / 2) {
      a = shared_in[t * SD + 2 * j];
      b = shared_in[t * SD + 2 * j + 1];
    } else {
      int k = 2 * (j - SD / 2);
      a = perdev[((size_t)d * TT + t) * PD + k];
      b = perdev[((size_t)d * TT + t) * PD + k + 1];
    }
    xs[i] = pack_h2(a, b);
  }
  __syncthreads();

#define WJ(j) ((j) < 16 ? w0[(j)] : ((j) < 32 ? w1[(j)-16] : w2[(j)-32]))
  for (int tt = 0; tt < GXTB; ++tt) {
    const unsigned* xr = &xs[tt * XPAIRS];
    float a0 = b0g, a1 = 0.f, a2 = 0.f, a3 = 0.f;
#pragma unroll
    for (int j = 0; j < XPAIRS; j += 4) {
      a0 = dot2(WJ(j + 0), xr[j + 0], a0);
      a1 = dot2(WJ(j + 1), xr[j + 1], a1);
      a2 = dot2(WJ(j + 2), xr[j + 2], a2);
      a3 = dot2(WJ(j + 3), xr[j + 3], a3);
    }
    gx[((size_t)d * TT + t0 + tt) * NG + g] = f16bits((a0 + a1) + (a2 + a3));
  }
#undef WJ
}

// ---------------------------------------------------------------------------
// Main recurrence. PRE=true: x-path preactivations read from gx (d_ws).
// PRE=false: fallback, x-path computed in-loop from LDS-resident W_ih0.
// ---------------------------------------------------------------------------
template <bool PRE>
__global__ __launch_bounds__(512, 2)
void lstm_pd_kernel(const float* __restrict__ shared_in,   // [T, S]
                    const float* __restrict__ perdev,      // [D, T, P]
                    const float* __restrict__ Wih0,        // [D, 4H, S+P]
                    const float* __restrict__ Whh0,        // [D, 4H, H]
                    const float* __restrict__ b0,          // [D, 4H]
                    const float* __restrict__ Wih1,        // [D, 4H, H]
                    const float* __restrict__ Whh1,        // [D, 4H, H]
                    const float* __restrict__ b1,          // [D, 4H]
                    const float* __restrict__ Wout,        // [D, H]
                    const float* __restrict__ bout,        // [D]
                    const unsigned short* __restrict__ gx, // [D, T, 4H] f16 (PRE)
                    float* __restrict__ out)               // [T, D]
{
  const int d = blockIdx.x;        // device
  const int g = threadIdx.x;       // gate row 0..511
  const int lane = g & 63;
  const int wave = g >> 6;

  __shared__ float act0_s[NG];                         // layer-0 gate activations
  __shared__ float act1_s[NG];                         // layer-1 gate activations
  __shared__ __align__(16) unsigned h0_s[HH / 2];      // h0 packed f16x2
  __shared__ __align__(16) unsigned h1_s[HH / 2];      // h1 packed f16x2
  __shared__ __align__(16) unsigned x_s[PRE ? 4 : (XPAIRS + 4)];
  __shared__ unsigned wih0_s[PRE ? 1 : (NG * WROW)];
  __shared__ float part_s[2];                          // output reduction partials

  // ---- setup: recurrent weights -> registers (f16 packed, SSA vectors) ----
  const float* pa = Whh0 + (size_t)(d * NG + g) * HH;
  uv16 wa0 = load16(pa + 0), wa1 = load16(pa + 32), wa2 = load16(pa + 64), wa3 = load16(pa + 96);
  const float* pi = Wih1 + (size_t)(d * NG + g) * HH;
  uv16 wi0 = load16(pi + 0), wi1 = load16(pi + 32), wi2 = load16(pi + 64), wi3 = load16(pi + 96);
  const float* ph = Whh1 + (size_t)(d * NG + g) * HH;
  uv16 wh0 = load16(ph + 0), wh1 = load16(ph + 32), wh2 = load16(ph + 64), wh3 = load16(ph + 96);

  float b0g = 0.f;
  if (!PRE) {
    // W_ih0 row g -> LDS (f16 packed)
    const float* p = Wih0 + (size_t)(d * NG + g) * XD;
    for (int j = 0; j < XPAIRS; ++j) wih0_s[g * WROW + j] = pack_h2(p[2 * j], p[2 * j + 1]);
    b0g = b0[d * NG + g];
  }
  const float b1g = b1[d * NG + g];
  const bool is_tanh_gate = ((g >> 7) == 2);  // rows 256..383 = candidate gate (i,f,g,o order)
  float c0 = 0.f, c1 = 0.f;                   // cell state, owned by threads g<128
  const float woutu = (g < HH) ? Wout[d * HH + g] : 0.f;
  const float boutd = bout[d];

  if (g < HH / 2) { h0_s[g] = 0u; h1_s[g] = 0u; }

  // prefetch x-path for t=0
  unsigned short gxc = 0, gxn = 0;
  float xa = 0.f, xb = 0.f;
  if (PRE) {
    gxc = gx[((size_t)d * TT + 0) * NG + g];
  } else if (g < XPAIRS) {
    xa = shared_in[0 * SD + 2 * g];
    if (g < SD / 2) {
      xa = shared_in[0 * SD + 2 * g];
      xb = shared_in[0 * SD + 2 * g + 1];
    } else {
      int k = 2 * (g - SD / 2);
      xa = perdev[((size_t)d * TT + 0) * PD + k];
      xb = perdev[((size_t)d * TT + 0) * PD + k + 1];
    }
  }

  __syncthreads();

  for (int t = 0; t < TT; ++t) {
    if (!PRE) {
      // publish x_t (fallback path only)
      if (g < XPAIRS) x_s[g] = pack_h2(xa, xb);
      __syncthreads();  // barrier 1 (fallback only)
    }

    // ---- phase 2: gates0[g] = gx + Whh0_row . h0 ----
    float a0, a1 = 0.f, a2 = 0.f, a3 = 0.f;
    if (PRE) {
      a0 = f16val(gxc);
    } else {
      a0 = b0g;
      const unsigned* wrow = &wih0_s[g * WROW];
#pragma unroll
      for (int j = 0; j < XPAIRS; j += 4) {
        a0 = dot2(wrow[j + 0], x_s[j + 0], a0);
        a1 = dot2(wrow[j + 1], x_s[j + 1], a1);
        a2 = dot2(wrow[j + 2], x_s[j + 2], a2);
        a3 = dot2(wrow[j + 3], x_s[j + 3], a3);
      }
    }
    {
      const uint4* h4 = (const uint4*)h0_s;
      dot16(wa0, h4, 0, a0, a1, a2, a3);
      dot16(wa1, h4, 4, a0, a1, a2, a3);
      SB();
      dot16(wa2, h4, 8, a0, a1, a2, a3);
      dot16(wa3, h4, 12, a0, a1, a2, a3);
      float pre = (a0 + a1) + (a2 + a3);
      act0_s[g] = is_tanh_gate ? fast_tanh(pre) : fast_sigmoid(pre);
    }
    __syncthreads();  // barrier 2

    // deferred output store for t-1 (part_s written in phase 5 of t-1, ordered by barrier 2)
    if (g == 0 && t > 0) out[(size_t)(t - 1) * DD + d] = part_s[0] + part_s[1] + boutd;

    // prefetch x-path for t+1 (latency hidden behind phases 2-4)
    if (PRE) {
      if (t + 1 < TT) gxn = gx[((size_t)d * TT + t + 1) * NG + g];
    } else if (g < XPAIRS && t + 1 < TT) {
      int tn = t + 1;
      if (g < SD / 2) {
        xa = shared_in[tn * SD + 2 * g];
        xb = shared_in[tn * SD + 2 * g + 1];
      } else {
        int k = 2 * (g - SD / 2);
        xa = perdev[((size_t)d * TT + tn) * PD + k];
        xb = perdev[((size_t)d * TT + tn) * PD + k + 1];
      }
    }

    // ---- phase 3: layer-0 cell update (threads 0..127) ----
    if (g < HH) {
      float ig = act0_s[g], fg = act0_s[g + 128], gg = act0_s[g + 256], og = act0_s[g + 384];
      c0 = __builtin_fmaf(fg, c0, ig * gg);
      float h0n = og * fast_tanh(c0);
      ((unsigned short*)h0_s)[g] = f16bits(h0n);
    }
    __syncthreads();  // barrier 3

    // ---- phase 4: gates1[g] = b1 + Wih1_row . h0_new + Whh1_row . h1 ----
    a0 = b1g; a1 = 0.f; a2 = 0.f; a3 = 0.f;
    {
      const uint4* h4 = (const uint4*)h0_s;
      dot16(wi0, h4, 0, a0, a1, a2, a3);
      dot16(wi1, h4, 4, a0, a1, a2, a3);
      SB();
      dot16(wi2, h4, 8, a0, a1, a2, a3);
      dot16(wi3, h4, 12, a0, a1, a2, a3);
      SB();
      const uint4* g4 = (const uint4*)h1_s;
      dot16(wh0, g4, 0, a0, a1, a2, a3);
      dot16(wh1, g4, 4, a0, a1, a2, a3);
      SB();
      dot16(wh2, g4, 8, a0, a1, a2, a3);
      dot16(wh3, g4, 12, a0, a1, a2, a3);
      float pre = (a0 + a1) + (a2 + a3);
      act1_s[g] = is_tanh_gate ? fast_tanh(pre) : fast_sigmoid(pre);
    }
    __syncthreads();  // barrier 4

    // ---- phase 5: layer-1 cell update + output partial (threads 0..127) ----
    // Runs concurrently with next iteration's phase 2 across threads; safe:
    // act1_s/act0_s are distinct buffers, h1_s readers (phase 4) are two
    // barriers downstream, part_s readers are one barrier downstream.
    if (g < HH) {
      float ig = act1_s[g], fg = act1_s[g + 128], gg = act1_s[g + 256], og = act1_s[g + 384];
      c1 = __builtin_fmaf(fg, c1, ig * gg);
      float h1n = og * fast_tanh(c1);
      ((unsigned short*)h1_s)[g] = f16bits(h1n);
      float p = woutu * h1n;
#pragma unroll
      for (int off = 32; off > 0; off >>= 1) p += __shfl_down(p, off, 64);
      if (lane == 0) part_s[wave] = p;
    }
    gxc = gxn;
  }

  __syncthreads();
  if (g == 0) out[(size_t)(TT - 1) * DD + d] = part_s[0] + part_s[1] + boutd;
}

extern "C" void kernel_launch(void* const* d_in, const int* in_sizes, int n_in,
                              void* d_out, int out_size, void* d_ws, size_t ws_size,
                              hipStream_t stream) {
  const float* shared_in = (const float*)d_in[0];
  const float* perdev    = (const float*)d_in[1];
  const float* Wih0      = (const float*)d_in[2];
  const float* Whh0      = (const float*)d_in[3];
  const float* b0        = (const float*)d_in[4];
  const float* Wih1      = (const float*)d_in[5];
  const float* Whh1      = (const float*)d_in[6];
  const float* b1        = (const float*)d_in[7];
  const float* Wout      = (const float*)d_in[8];
  const float* bout      = (const float*)d_in[9];
  float* out = (float*)d_out;

  const size_t gx_bytes = (size_t)DD * TT * NG * sizeof(unsigned short);  // 128 MB
  if (ws_size >= gx_bytes) {
    unsigned short* gx = (unsigned short*)d_ws;
    gx_kernel<<<dim3(TT / GXTB, DD), dim3(512), 0, stream>>>(shared_in, perdev, Wih0, b0, gx);
    lstm_pd_kernel<true><<<dim3(DD), dim3(NG), 0, stream>>>(
        shared_in, perdev, Wih0, Whh0, b0, Wih1, Whh1, b1, Wout, bout, gx, out);
  } else {
    lstm_pd_kernel<false><<<dim3(DD), dim3(NG), 0, stream>>>(
        shared_in, perdev, Wih0, Whh0, b0, Wih1, Whh1, b1, Wout, bout, nullptr, out);
  }
}